// Round 6
// baseline (134.917 us; speedup 1.0000x reference)
//
#include <hip/hip_runtime.h>
#include <limits.h>
#include <stdint.h>

#define ALPHA 0.2f
#define HALFA 0.1f
static constexpr int N = 8192;
static constexpr int D = 128;
static constexpr int C = 512;
static constexpr int BT = 128;                    // tile edge (points per tile)
static constexpr int GR = D / 8;                  // 16 granules (half8) per row
static constexpr int SL = BT + 1;                 // padded row count per granule
static constexpr int MAXG = 48;                   // e-list capacity (mean 16, 8 sigma)
static constexpr int NB = N / BT;                 // 64 row/col panels
static constexpr int NT1B = 256;                  // term1 blocks: 8 class-panels x 32 j-groups
static constexpr int NSP = NB / 2;                // 32 superpanels
static constexpr int SPB = 16;                    // blocks per superpanel
static constexpr int GRID = NT1B + NSP * SPB;     // 768 = 3 blocks/CU x 256 CUs

using half8    = __attribute__((ext_vector_type(8))) _Float16;
using floatx16 = __attribute__((ext_vector_type(16))) float;

__device__ __forceinline__ floatx16 zerov() { floatx16 v = {0.f}; return v; }

__device__ __forceinline__ half8 cvt8(float4 v0, float4 v1) {
    half8 h;
    h[0] = (_Float16)v0.x; h[1] = (_Float16)v0.y; h[2] = (_Float16)v0.z; h[3] = (_Float16)v0.w;
    h[4] = (_Float16)v1.x; h[5] = (_Float16)v1.y; h[6] = (_Float16)v1.z; h[7] = (_Float16)v1.w;
    return h;
}

__device__ __forceinline__ float ss8(float4 v0, float4 v1) {
    return v0.x*v0.x + v0.y*v0.y + v0.z*v0.z + v0.w*v0.w
         + v1.x*v1.x + v1.y*v1.y + v1.z*v1.z + v1.w*v1.w;
}

// superpanel k: tiles 0..lenA-1 are (br=k, bc=k+t); rest are (br=63-k, bc=63-k+t-lenA)
__device__ __forceinline__ void dec_sp(int k, int t, int lenA, int& br, int& bc) {
    if (t < lenA) { br = k;      bc = k + t; }
    else          { br = 63 - k; bc = 63 - k + (t - lenA); }
}

// ---- k_prep: anchors + xh (fp16) + sq + ap + GLOBAL e-lists ---------------------------
// egrid is memset to 0x7F (3.396e38) so padded slots self-exclude in the hinge loop.

__launch_bounds__(256)
__global__ void k_prep(const float* __restrict__ x, const int* __restrict__ labels,
                       _Float16* __restrict__ xh, float* __restrict__ sq,
                       int* __restrict__ anchorg, float* __restrict__ ap,
                       int* __restrict__ ecnt, float* __restrict__ egrid,
                       float* __restrict__ out) {
    __shared__ int sAnc[C];
    const int tid = threadIdx.x;
    if (blockIdx.x == 0 && tid == 0) out[0] = 0.f;
    for (int i = tid; i < C; i += 256) sAnc[i] = INT_MAX;
    __syncthreads();
    const int4* lab4 = (const int4*)labels;
    for (int t = tid; t < N / 4; t += 256) {
        int4 lv = lab4[t];
        int base = 4 * t;
        atomicMin(&sAnc[lv.x], base);
        atomicMin(&sAnc[lv.y], base + 1);
        atomicMin(&sAnc[lv.z], base + 2);
        atomicMin(&sAnc[lv.w], base + 3);
    }
    __syncthreads();
    if (tid < 2) {
        int c = blockIdx.x * 2 + tid;
        int a = sAnc[c];
        anchorg[c] = (a == INT_MAX) ? -1 : a;
    }

    const int r = blockIdx.x * 32 + (tid >> 3);
    const int sub = tid & 7;
    const float4* src = (const float4*)(x + (size_t)r * D) + sub * 4;
    half8* dst = (half8*)(xh + (size_t)r * D) + sub * 2;
    half8 hj[2];
    float ssj = 0.f;
#pragma unroll
    for (int i = 0; i < 2; ++i) {
        float4 v0 = src[2 * i], v1 = src[2 * i + 1];
        hj[i] = cvt8(v0, v1);
        dst[i] = hj[i];
        ssj += ss8(v0, v1);
    }
    ssj += __shfl_xor(ssj, 1); ssj += __shfl_xor(ssj, 2); ssj += __shfl_xor(ssj, 4);

    const int lab = labels[r];
    const int a = sAnc[lab];
    const float4* asrc = (const float4*)(x + (size_t)a * D) + sub * 4;
    float ssa = 0.f, dot = 0.f;
#pragma unroll
    for (int i = 0; i < 2; ++i) {
        float4 a0 = asrc[2 * i], a1 = asrc[2 * i + 1];
        half8 ha = cvt8(a0, a1);
        ssa += ss8(a0, a1);
#pragma unroll
        for (int e = 0; e < 8; ++e) dot = fmaf((float)ha[e], (float)hj[i][e], dot);
    }
    ssa += __shfl_xor(ssa, 1); ssa += __shfl_xor(ssa, 2); ssa += __shfl_xor(ssa, 4);
    dot += __shfl_xor(dot, 1); dot += __shfl_xor(dot, 2); dot += __shfl_xor(dot, 4);
    if (sub == 0) {
        float apv = ssa + ssj - 2.f * dot;
        sq[r] = ssj;
        ap[r] = apv;
        if (r != a) {   // append to the class e-list (anchor itself excluded)
            int slot = atomicAdd(&ecnt[lab], 1);
            if (slot < MAXG) egrid[(size_t)lab * MAXG + slot] = apv + HALFA;
        }
    }
}

// ---- k_main: 768 single-shot blocks, 3/CU, branch-free compensated hinges -------------
// term1 (blocks 0..255): class-panel walker, 2 j-tiles, A/e-lists loaded once.
// term2 (blocks 256..767): superpanel walker (proven R5 structure).

__launch_bounds__(512, 6)
__global__ void k_main(const _Float16* __restrict__ xh, const int* __restrict__ labels,
                       const int* __restrict__ anchor, const float* __restrict__ sq,
                       const float* __restrict__ ap, const int* __restrict__ ecnt,
                       const float* __restrict__ egrid, float* __restrict__ out) {
    __shared__ __align__(16) _Float16 BsH[GR * SL * 8];   // 33024 B, K-major [granule][row]
    __shared__ __align__(16) float sge[64 * MAXG];        // 12288 B e-lists
    __shared__ float4 rowE[BT];
    __shared__ float4 colE[2][BT];
    __shared__ int   sArow[64];
    __shared__ float sSqA[64];
    __shared__ int   sCnt[64];
    __shared__ float wsum[8];
    half8* Bs = (half8*)BsH;

    const int tid = threadIdx.x;
    const int lane = tid & 63, w = tid >> 6;
    const int m = lane & 31, q = lane >> 5;
    const int sg = tid & 15, sr0 = tid >> 4;   // staging: granule, row base
    float local = 0.f;
    int cnt = 0;                                // hinge slots evaluated (for +h*cnt)

    if ((int)blockIdx.x < NT1B) {
        // ---------------- term1: class panel (64 anchors) x 2 j-tiles ----------------
        const int cb = blockIdx.x >> 5, jg = blockIdx.x & 31;
        const int c0 = cb * 64;
        const int wr2 = w >> 2, wc4 = w & 3;   // 2 row-groups x 4 col-groups

        if (tid < 64) {
            int c = c0 + tid;
            int a = anchor[c];
            int ar = (a < 0) ? 0 : a;          // dummy (absent class has cnt 0)
            sArow[tid] = ar;
            sSqA[tid] = sq[ar];
            int n = ecnt[c];
            sCnt[tid] = (n > MAXG) ? MAXG : n;
        }
        {   // bulk-copy 64 class e-lists (pre-padded with 3.4e38)
            const float4* srcv = (const float4*)(egrid + (size_t)c0 * MAXG);
            float4* dstv = (float4*)sge;
            dstv[tid] = srcv[tid];
            if (tid < 64 * MAXG / 4 - 512) dstv[tid + 512] = srcv[tid + 512];
        }
        half8 breg[4];
        {   // prologue: prefetch tile0 B + colE[0]
            int j0 = (jg * 2) * BT;
#pragma unroll
            for (int i = 0; i < 4; ++i)
                breg[i] = *((const half8*)(xh + (size_t)(j0 + sr0 + 32 * i) * D) + sg);
            if (tid < BT) {
                int j = j0 + tid;
                colE[0][tid] = make_float4(sq[j], __int_as_float(labels[j]), 0.f, 0.f);
            }
        }
        __syncthreads();

        half8 af[8];
        {   // A fragments: gathered anchor rows, once per block
            int arow = sArow[wr2 * 32 + m];
            const half8* aptr = (const half8*)(xh + (size_t)arow * D) + q;
#pragma unroll
            for (int k = 0; k < 8; ++k) af[k] = aptr[2 * k];
        }

        for (int t = 0; t < 2; ++t) {
#pragma unroll
            for (int i = 0; i < 4; ++i)
                Bs[sg * SL + sr0 + 32 * i] = breg[i];
            __syncthreads();

            if (t == 0) {   // prefetch tile1
                int j1 = (jg * 2 + 1) * BT;
#pragma unroll
                for (int i = 0; i < 4; ++i)
                    breg[i] = *((const half8*)(xh + (size_t)(j1 + sr0 + 32 * i) * D) + sg);
                if (tid < BT) {
                    int j = j1 + tid;
                    colE[1][tid] = make_float4(sq[j], __int_as_float(labels[j]), 0.f, 0.f);
                }
            }

            floatx16 acc = zerov();
#pragma unroll
            for (int k = 0; k < 8; ++k) {
                half8 b0 = Bs[(2 * k + q) * SL + wc4 * 32 + m];
                acc = __builtin_amdgcn_mfma_f32_32x32x16_f16(af[k], b0, acc, 0, 0, 0);
            }

            float4 cj = colE[t][wc4 * 32 + m];
            float sqj = cj.x; int labj = __float_as_int(cj.y);
#pragma unroll
            for (int rr = 0; rr < 16; ++rr) {
                int row = wr2 * 32 + (rr & 3) + 8 * (rr >> 2) + 4 * q;
                float Dv = fmaf(-2.f, acc[rr], sSqA[row] + sqj);
                Dv = (labj != c0 + row) ? Dv : 3.0e38f;       // fold label mask into base
                int nf = (sCnt[row] + 3) & ~3;
                cnt += nf;
                for (int gb = 0; gb < nf; gb += 4) {
                    float4 ev = *(const float4*)&sge[row * MAXG + gb];
                    float u;
                    u = ev.x - Dv; local += (__builtin_fabsf(u) < HALFA) ? u : -HALFA;
                    u = ev.y - Dv; local += (__builtin_fabsf(u) < HALFA) ? u : -HALFA;
                    u = ev.z - Dv; local += (__builtin_fabsf(u) < HALFA) ? u : -HALFA;
                    u = ev.w - Dv; local += (__builtin_fabsf(u) < HALFA) ? u : -HALFA;
                }
            }
            __syncthreads();
        }
    } else {
        // ---------------- term2: superpanel walker ----------------
        const int bi = blockIdx.x - NT1B;
        const int k = bi >> 4, p = bi & 15;
        const int lenA = 64 - k;
        const int wr = w >> 1, wc = w & 1;     // 4 row-groups x 2 col-groups
        int cbuf = 0, cur_br = -1;
        half8 af[8], breg[4];

        {   // prologue: prefetch first tile's B and colE[0]
            int br0, bc0; dec_sp(k, p, lenA, br0, bc0);
            int j0 = bc0 * BT;
#pragma unroll
            for (int i = 0; i < 4; ++i)
                breg[i] = *((const half8*)(xh + (size_t)(j0 + sr0 + 32 * i) * D) + sg);
            if (tid < BT) {
                int j = j0 + tid;
                int lj = labels[j]; int a = anchor[lj];
                float sqj = sq[j];
                float e2 = (j == a) ? -1e30f : ap[j] + HALFA - sqj;
                colE[0][tid] = make_float4(e2, __int_as_float(lj), sqj, 0.f);
            }
        }

        for (int t = p; t < 65; t += SPB) {
            int br, bc; dec_sp(k, t, lenA, br, bc);
            const int i0 = br * BT;
            const bool diag = (br == bc);

            if (br != cur_br) {
                cur_br = br;
                const half8* aptr = (const half8*)(xh + (size_t)(i0 + wr * 32 + m) * D) + q;
#pragma unroll
                for (int kk = 0; kk < 8; ++kk) af[kk] = aptr[2 * kk];
                if (tid < BT) {
                    int i = i0 + tid;
                    int li = labels[i]; int a = anchor[li];
                    float sqi = sq[i];
                    float e2 = (i == a) ? -1e30f : ap[i] + HALFA - sqi;
                    rowE[tid] = make_float4(e2, __int_as_float(li), sqi, 0.f);
                }
            }

#pragma unroll
            for (int i = 0; i < 4; ++i)
                Bs[sg * SL + sr0 + 32 * i] = breg[i];
            __syncthreads();

            if (t + SPB < 65) {   // prefetch next tile
                int brn, bcn; dec_sp(k, t + SPB, lenA, brn, bcn);
                int j0n = bcn * BT;
#pragma unroll
                for (int i = 0; i < 4; ++i)
                    breg[i] = *((const half8*)(xh + (size_t)(j0n + sr0 + 32 * i) * D) + sg);
                if (tid < BT) {
                    int j = j0n + tid;
                    int lj = labels[j]; int a = anchor[lj];
                    float sqj = sq[j];
                    float e2 = (j == a) ? -1e30f : ap[j] + HALFA - sqj;
                    colE[cbuf ^ 1][tid] = make_float4(e2, __int_as_float(lj), sqj, 0.f);
                }
            }

            floatx16 acc0 = zerov(), acc1 = zerov();
#pragma unroll
            for (int kk = 0; kk < 8; ++kk) {
                half8 b0 = Bs[(2 * kk + q) * SL + wc * 64 + m];
                half8 b1 = Bs[(2 * kk + q) * SL + wc * 64 + 32 + m];
                acc0 = __builtin_amdgcn_mfma_f32_32x32x16_f16(af[kk], b0, acc0, 0, 0, 0);
                acc1 = __builtin_amdgcn_mfma_f32_32x32x16_f16(af[kk], b1, acc1, 0, 0, 0);
            }

            float sqjv[2], e2j[2]; int labj[2];
            { float4 cj = colE[cbuf][wc * 64 + m];      e2j[0] = cj.x; labj[0] = __float_as_int(cj.y); sqjv[0] = cj.z; }
            { float4 cj = colE[cbuf][wc * 64 + 32 + m]; e2j[1] = cj.x; labj[1] = __float_as_int(cj.y); sqjv[1] = cj.z; }

#pragma unroll
            for (int rr = 0; rr < 16; ++rr) {
                int row = wr * 32 + (rr & 3) + 8 * (rr >> 2) + 4 * q;
                float4 re = rowE[row];
                float e2i = re.x, sqi = re.z;
                int labi = __float_as_int(re.y);
#pragma unroll
                for (int tn = 0; tn < 2; ++tn) {
                    float dot = (tn == 0) ? acc0[rr] : acc1[rr];
                    bool ne = (labi != labj[tn]);
                    float b1 = ne ? (e2i - sqjv[tn]) : 3.0e38f;
                    float u2 = fmaf(2.f, dot, b1);
                    local += (__builtin_fabsf(u2) < HALFA) ? u2 : -HALFA;
                    if (!diag) {
                        float b2 = ne ? (e2j[tn] - sqi) : 3.0e38f;
                        float u2b = fmaf(2.f, dot, b2);
                        local += (__builtin_fabsf(u2b) < HALFA) ? u2b : -HALFA;
                    }
                }
            }
            cnt += diag ? 32 : 64;
            cbuf ^= 1;
            __syncthreads();
        }
    }

    // compensation for the -HALFA branchless accumulation, then block reduce
    local += HALFA * (float)cnt;
#pragma unroll
    for (int off = 32; off; off >>= 1) local += __shfl_down(local, off);
    if (lane == 0) wsum[w] = local;
    __syncthreads();
    if (tid == 0) {
        float s = 0.f;
#pragma unroll
        for (int i = 0; i < 8; ++i) s += wsum[i];
        atomicAdd(out, s);
    }
}

// ---------------- launch ----------------

extern "C" void kernel_launch(void* const* d_in, const int* in_sizes, int n_in,
                              void* d_out, int out_size, void* d_ws, size_t ws_size,
                              hipStream_t stream) {
    const float* x = (const float*)d_in[0];
    const int* labels = (const int*)d_in[1];
    float* out = (float*)d_out;

    char* p = (char*)d_ws;
    int* anchor = (int*)p;        p += C * 4;
    float* sq = (float*)p;        p += N * 4;
    float* ap = (float*)p;        p += N * 4;
    int* ecnt = (int*)p;          p += C * 4;
    float* egrid = (float*)p;     p += (size_t)C * MAXG * 4;
    p = (char*)(((uintptr_t)p + 255) & ~(uintptr_t)255);
    _Float16* xh = (_Float16*)p;  // N*D*2 = 2 MB

    hipMemsetAsync(ecnt, 0, C * 4, stream);
    hipMemsetAsync(egrid, 0x7F, (size_t)C * MAXG * 4, stream);   // 3.396e38 pads
    k_prep<<<N / 32, 256, 0, stream>>>(x, labels, xh, sq, anchor, ap, ecnt, egrid, out);
    k_main<<<GRID, 512, 0, stream>>>(xh, labels, anchor, sq, ap, ecnt, egrid, out);
}

// Round 7
// 125.348 us; speedup vs baseline: 1.0763x; 1.0763x over previous
//
#include <hip/hip_runtime.h>
#include <limits.h>
#include <stdint.h>

#define ALPHA 0.2f
#define HALFA 0.1f
static constexpr int N = 8192;
static constexpr int D = 128;
static constexpr int C = 512;
static constexpr int BT = 128;                    // tile edge (points per tile)
static constexpr int GR = D / 8;                  // 16 granules (half8) per row
static constexpr int SL = BT + 1;                 // padded row count per granule
static constexpr int MAXG = 48;                   // e-list capacity (mean 16, 8 sigma)
static constexpr int NB = N / BT;                 // 64 row/col panels
static constexpr int NT1B = 256;                  // term1 blocks: 8 class-panels x 32 j-groups
static constexpr int NSP = NB / 2;                // 32 superpanels
static constexpr int SPB = 16;                    // blocks per superpanel
static constexpr int GRID = NT1B + NSP * SPB;     // 768 = 3 blocks/CU x 256 CUs

using half8    = __attribute__((ext_vector_type(8))) _Float16;
using floatx16 = __attribute__((ext_vector_type(16))) float;

__device__ __forceinline__ floatx16 zerov() { floatx16 v = {0.f}; return v; }

__device__ __forceinline__ half8 cvt8(float4 v0, float4 v1) {
    half8 h;
    h[0] = (_Float16)v0.x; h[1] = (_Float16)v0.y; h[2] = (_Float16)v0.z; h[3] = (_Float16)v0.w;
    h[4] = (_Float16)v1.x; h[5] = (_Float16)v1.y; h[6] = (_Float16)v1.z; h[7] = (_Float16)v1.w;
    return h;
}

__device__ __forceinline__ float ss8(float4 v0, float4 v1) {
    return v0.x*v0.x + v0.y*v0.y + v0.z*v0.z + v0.w*v0.w
         + v1.x*v1.x + v1.y*v1.y + v1.z*v1.z + v1.w*v1.w;
}

// superpanel k: tiles 0..lenA-1 are (br=k, bc=k+t); rest are (br=63-k, bc=63-k+t-lenA)
__device__ __forceinline__ void dec_sp(int k, int t, int lenA, int& br, int& bc) {
    if (t < lenA) { br = k;      bc = k + t; }
    else          { br = 63 - k; bc = 63 - k + (t - lenA); }
}

// ---- k_prep: anchors + xh (fp16) + sq + ap + GLOBAL e-lists ---------------------------
// egrid is memset to 0x7F (3.396e38) so padded slots self-exclude in the hinge loop.

__launch_bounds__(256)
__global__ void k_prep(const float* __restrict__ x, const int* __restrict__ labels,
                       _Float16* __restrict__ xh, float* __restrict__ sq,
                       int* __restrict__ anchorg, float* __restrict__ ap,
                       int* __restrict__ ecnt, float* __restrict__ egrid,
                       float* __restrict__ out) {
    __shared__ int sAnc[C];
    const int tid = threadIdx.x;
    if (blockIdx.x == 0 && tid == 0) out[0] = 0.f;
    for (int i = tid; i < C; i += 256) sAnc[i] = INT_MAX;
    __syncthreads();
    const int4* lab4 = (const int4*)labels;
    for (int t = tid; t < N / 4; t += 256) {
        int4 lv = lab4[t];
        int base = 4 * t;
        atomicMin(&sAnc[lv.x], base);
        atomicMin(&sAnc[lv.y], base + 1);
        atomicMin(&sAnc[lv.z], base + 2);
        atomicMin(&sAnc[lv.w], base + 3);
    }
    __syncthreads();
    if (tid < 2) {
        int c = blockIdx.x * 2 + tid;
        int a = sAnc[c];
        anchorg[c] = (a == INT_MAX) ? -1 : a;
    }

    const int r = blockIdx.x * 32 + (tid >> 3);
    const int sub = tid & 7;
    const float4* src = (const float4*)(x + (size_t)r * D) + sub * 4;
    half8* dst = (half8*)(xh + (size_t)r * D) + sub * 2;
    half8 hj[2];
    float ssj = 0.f;
#pragma unroll
    for (int i = 0; i < 2; ++i) {
        float4 v0 = src[2 * i], v1 = src[2 * i + 1];
        hj[i] = cvt8(v0, v1);
        dst[i] = hj[i];
        ssj += ss8(v0, v1);
    }
    ssj += __shfl_xor(ssj, 1); ssj += __shfl_xor(ssj, 2); ssj += __shfl_xor(ssj, 4);

    const int lab = labels[r];
    const int a = sAnc[lab];
    const float4* asrc = (const float4*)(x + (size_t)a * D) + sub * 4;
    float ssa = 0.f, dot = 0.f;
#pragma unroll
    for (int i = 0; i < 2; ++i) {
        float4 a0 = asrc[2 * i], a1 = asrc[2 * i + 1];
        half8 ha = cvt8(a0, a1);
        ssa += ss8(a0, a1);
#pragma unroll
        for (int e = 0; e < 8; ++e) dot = fmaf((float)ha[e], (float)hj[i][e], dot);
    }
    ssa += __shfl_xor(ssa, 1); ssa += __shfl_xor(ssa, 2); ssa += __shfl_xor(ssa, 4);
    dot += __shfl_xor(dot, 1); dot += __shfl_xor(dot, 2); dot += __shfl_xor(dot, 4);
    if (sub == 0) {
        float apv = ssa + ssj - 2.f * dot;
        sq[r] = ssj;
        ap[r] = apv;
        if (r != a) {   // append to the class e-list (anchor itself excluded)
            int slot = atomicAdd(&ecnt[lab], 1);
            if (slot < MAXG) egrid[(size_t)lab * MAXG + slot] = apv + HALFA;
        }
    }
}

// ---- k_main: 768 single-shot blocks, LDS sized for 3/CU, branch-free hinges -----------
// term1 (blocks 0..255): class-panel walker, 2 j-tiles, A/e-lists loaded once.
// term2 (blocks 256..767): superpanel walker (R5-proven structure).
// __launch_bounds__(512,2): R5-proven — compiler picks ~60 VGPR with ZERO spill;
// tighter bounds (R4 cap 64, R6 min-6-waves) both caused catastrophic scratch spills.

__launch_bounds__(512, 2)
__global__ void k_main(const _Float16* __restrict__ xh, const int* __restrict__ labels,
                       const int* __restrict__ anchor, const float* __restrict__ sq,
                       const float* __restrict__ ap, const int* __restrict__ ecnt,
                       const float* __restrict__ egrid, float* __restrict__ out) {
    __shared__ __align__(16) _Float16 BsH[GR * SL * 8];   // 33024 B, K-major [granule][row]
    __shared__ __align__(16) float sge[64 * MAXG];        // 12288 B e-lists
    __shared__ float4 rowE[BT];
    __shared__ float4 colE[2][BT];
    __shared__ int   sArow[64];
    __shared__ float sSqA[64];
    __shared__ int   sCnt[64];
    __shared__ float wsum[8];
    half8* Bs = (half8*)BsH;

    const int tid = threadIdx.x;
    const int lane = tid & 63, w = tid >> 6;
    const int m = lane & 31, q = lane >> 5;
    const int sg = tid & 15, sr0 = tid >> 4;   // staging: granule, row base
    float local = 0.f;
    int cnt = 0;                                // hinge slots evaluated (for +h*cnt)

    if ((int)blockIdx.x < NT1B) {
        // ---------------- term1: class panel (64 anchors) x 2 j-tiles ----------------
        const int cb = blockIdx.x >> 5, jg = blockIdx.x & 31;
        const int c0 = cb * 64;
        const int wr2 = w >> 2, wc4 = w & 3;   // 2 row-groups x 4 col-groups

        if (tid < 64) {
            int c = c0 + tid;
            int a = anchor[c];
            int ar = (a < 0) ? 0 : a;          // dummy (absent class has cnt 0)
            sArow[tid] = ar;
            sSqA[tid] = sq[ar];
            int n = ecnt[c];
            sCnt[tid] = (n > MAXG) ? MAXG : n;
        }
        {   // bulk-copy 64 class e-lists (pre-padded with 3.4e38)
            const float4* srcv = (const float4*)(egrid + (size_t)c0 * MAXG);
            float4* dstv = (float4*)sge;
            dstv[tid] = srcv[tid];
            if (tid < 64 * MAXG / 4 - 512) dstv[tid + 512] = srcv[tid + 512];
        }
        half8 breg[4];
        {   // prologue: prefetch tile0 B + colE[0]
            int j0 = (jg * 2) * BT;
#pragma unroll
            for (int i = 0; i < 4; ++i)
                breg[i] = *((const half8*)(xh + (size_t)(j0 + sr0 + 32 * i) * D) + sg);
            if (tid < BT) {
                int j = j0 + tid;
                colE[0][tid] = make_float4(sq[j], __int_as_float(labels[j]), 0.f, 0.f);
            }
        }
        __syncthreads();

        half8 af[8];
        {   // A fragments: gathered anchor rows, once per block
            int arow = sArow[wr2 * 32 + m];
            const half8* aptr = (const half8*)(xh + (size_t)arow * D) + q;
#pragma unroll
            for (int k = 0; k < 8; ++k) af[k] = aptr[2 * k];
        }

        for (int t = 0; t < 2; ++t) {
#pragma unroll
            for (int i = 0; i < 4; ++i)
                Bs[sg * SL + sr0 + 32 * i] = breg[i];
            __syncthreads();

            if (t == 0) {   // prefetch tile1
                int j1 = (jg * 2 + 1) * BT;
#pragma unroll
                for (int i = 0; i < 4; ++i)
                    breg[i] = *((const half8*)(xh + (size_t)(j1 + sr0 + 32 * i) * D) + sg);
                if (tid < BT) {
                    int j = j1 + tid;
                    colE[1][tid] = make_float4(sq[j], __int_as_float(labels[j]), 0.f, 0.f);
                }
            }

            floatx16 acc = zerov();
#pragma unroll
            for (int k = 0; k < 8; ++k) {
                half8 b0 = Bs[(2 * k + q) * SL + wc4 * 32 + m];
                acc = __builtin_amdgcn_mfma_f32_32x32x16_f16(af[k], b0, acc, 0, 0, 0);
            }

            float4 cj = colE[t][wc4 * 32 + m];
            float sqj = cj.x; int labj = __float_as_int(cj.y);
#pragma unroll
            for (int rr = 0; rr < 16; ++rr) {
                int row = wr2 * 32 + (rr & 3) + 8 * (rr >> 2) + 4 * q;
                float Dv = fmaf(-2.f, acc[rr], sSqA[row] + sqj);
                Dv = (labj != c0 + row) ? Dv : 3.0e38f;       // fold label mask into base
                int nf = (sCnt[row] + 3) & ~3;
                cnt += nf;
                for (int gb = 0; gb < nf; gb += 4) {
                    float4 ev = *(const float4*)&sge[row * MAXG + gb];
                    float u;
                    u = ev.x - Dv; local += (__builtin_fabsf(u) < HALFA) ? u : -HALFA;
                    u = ev.y - Dv; local += (__builtin_fabsf(u) < HALFA) ? u : -HALFA;
                    u = ev.z - Dv; local += (__builtin_fabsf(u) < HALFA) ? u : -HALFA;
                    u = ev.w - Dv; local += (__builtin_fabsf(u) < HALFA) ? u : -HALFA;
                }
            }
            __syncthreads();
        }
    } else {
        // ---------------- term2: superpanel walker ----------------
        const int bi = blockIdx.x - NT1B;
        const int k = bi >> 4, p = bi & 15;
        const int lenA = 64 - k;
        const int wr = w >> 1, wc = w & 1;     // 4 row-groups x 2 col-groups
        int cbuf = 0, cur_br = -1;
        half8 af[8], breg[4];

        {   // prologue: prefetch first tile's B and colE[0]
            int br0, bc0; dec_sp(k, p, lenA, br0, bc0);
            int j0 = bc0 * BT;
#pragma unroll
            for (int i = 0; i < 4; ++i)
                breg[i] = *((const half8*)(xh + (size_t)(j0 + sr0 + 32 * i) * D) + sg);
            if (tid < BT) {
                int j = j0 + tid;
                int lj = labels[j]; int a = anchor[lj];
                float sqj = sq[j];
                float e2 = (j == a) ? -1e30f : ap[j] + HALFA - sqj;
                colE[0][tid] = make_float4(e2, __int_as_float(lj), sqj, 0.f);
            }
        }

        for (int t = p; t < 65; t += SPB) {
            int br, bc; dec_sp(k, t, lenA, br, bc);
            const int i0 = br * BT;
            const bool diag = (br == bc);

            if (br != cur_br) {
                cur_br = br;
                const half8* aptr = (const half8*)(xh + (size_t)(i0 + wr * 32 + m) * D) + q;
#pragma unroll
                for (int kk = 0; kk < 8; ++kk) af[kk] = aptr[2 * kk];
                if (tid < BT) {
                    int i = i0 + tid;
                    int li = labels[i]; int a = anchor[li];
                    float sqi = sq[i];
                    float e2 = (i == a) ? -1e30f : ap[i] + HALFA - sqi;
                    rowE[tid] = make_float4(e2, __int_as_float(li), sqi, 0.f);
                }
            }

#pragma unroll
            for (int i = 0; i < 4; ++i)
                Bs[sg * SL + sr0 + 32 * i] = breg[i];
            __syncthreads();

            if (t + SPB < 65) {   // prefetch next tile
                int brn, bcn; dec_sp(k, t + SPB, lenA, brn, bcn);
                int j0n = bcn * BT;
#pragma unroll
                for (int i = 0; i < 4; ++i)
                    breg[i] = *((const half8*)(xh + (size_t)(j0n + sr0 + 32 * i) * D) + sg);
                if (tid < BT) {
                    int j = j0n + tid;
                    int lj = labels[j]; int a = anchor[lj];
                    float sqj = sq[j];
                    float e2 = (j == a) ? -1e30f : ap[j] + HALFA - sqj;
                    colE[cbuf ^ 1][tid] = make_float4(e2, __int_as_float(lj), sqj, 0.f);
                }
            }

            floatx16 acc0 = zerov(), acc1 = zerov();
#pragma unroll
            for (int kk = 0; kk < 8; ++kk) {
                half8 b0 = Bs[(2 * kk + q) * SL + wc * 64 + m];
                half8 b1 = Bs[(2 * kk + q) * SL + wc * 64 + 32 + m];
                acc0 = __builtin_amdgcn_mfma_f32_32x32x16_f16(af[kk], b0, acc0, 0, 0, 0);
                acc1 = __builtin_amdgcn_mfma_f32_32x32x16_f16(af[kk], b1, acc1, 0, 0, 0);
            }

            float sqjv[2], e2j[2]; int labj[2];
            { float4 cj = colE[cbuf][wc * 64 + m];      e2j[0] = cj.x; labj[0] = __float_as_int(cj.y); sqjv[0] = cj.z; }
            { float4 cj = colE[cbuf][wc * 64 + 32 + m]; e2j[1] = cj.x; labj[1] = __float_as_int(cj.y); sqjv[1] = cj.z; }

#pragma unroll
            for (int rr = 0; rr < 16; ++rr) {
                int row = wr * 32 + (rr & 3) + 8 * (rr >> 2) + 4 * q;
                float4 re = rowE[row];
                float e2i = re.x, sqi = re.z;
                int labi = __float_as_int(re.y);
#pragma unroll
                for (int tn = 0; tn < 2; ++tn) {
                    float dot = (tn == 0) ? acc0[rr] : acc1[rr];
                    bool ne = (labi != labj[tn]);
                    float b1 = ne ? (e2i - sqjv[tn]) : 3.0e38f;
                    float u2 = fmaf(2.f, dot, b1);
                    local += (__builtin_fabsf(u2) < HALFA) ? u2 : -HALFA;
                    if (!diag) {
                        float b2 = ne ? (e2j[tn] - sqi) : 3.0e38f;
                        float u2b = fmaf(2.f, dot, b2);
                        local += (__builtin_fabsf(u2b) < HALFA) ? u2b : -HALFA;
                    }
                }
            }
            cnt += diag ? 32 : 64;
            cbuf ^= 1;
            __syncthreads();
        }
    }

    // compensation for the -HALFA branchless accumulation, then block reduce
    local += HALFA * (float)cnt;
#pragma unroll
    for (int off = 32; off; off >>= 1) local += __shfl_down(local, off);
    if (lane == 0) wsum[w] = local;
    __syncthreads();
    if (tid == 0) {
        float s = 0.f;
#pragma unroll
        for (int i = 0; i < 8; ++i) s += wsum[i];
        atomicAdd(out, s);
    }
}

// ---------------- launch ----------------

extern "C" void kernel_launch(void* const* d_in, const int* in_sizes, int n_in,
                              void* d_out, int out_size, void* d_ws, size_t ws_size,
                              hipStream_t stream) {
    const float* x = (const float*)d_in[0];
    const int* labels = (const int*)d_in[1];
    float* out = (float*)d_out;

    char* p = (char*)d_ws;
    int* anchor = (int*)p;        p += C * 4;
    float* sq = (float*)p;        p += N * 4;
    float* ap = (float*)p;        p += N * 4;
    int* ecnt = (int*)p;          p += C * 4;
    float* egrid = (float*)p;     p += (size_t)C * MAXG * 4;
    p = (char*)(((uintptr_t)p + 255) & ~(uintptr_t)255);
    _Float16* xh = (_Float16*)p;  // N*D*2 = 2 MB

    hipMemsetAsync(ecnt, 0, C * 4, stream);
    hipMemsetAsync(egrid, 0x7F, (size_t)C * MAXG * 4, stream);   // 3.396e38 pads
    k_prep<<<N / 32, 256, 0, stream>>>(x, labels, xh, sq, anchor, ap, ecnt, egrid, out);
    k_main<<<GRID, 512, 0, stream>>>(xh, labels, anchor, sq, ap, ecnt, egrid, out);
}

// Round 8
// 107.413 us; speedup vs baseline: 1.2561x; 1.1670x over previous
//
#include <hip/hip_runtime.h>
#include <limits.h>
#include <stdint.h>

#define ALPHA 0.2f
#define HALFA 0.1f
static constexpr int N = 8192;
static constexpr int D = 128;
static constexpr int C = 512;
static constexpr int BT = 128;                    // tile edge (points per tile)
static constexpr int GR = D / 8;                  // 16 granules (half8) per row
static constexpr int SL = BT + 1;                 // padded row count per granule
static constexpr int MAXG = 48;                   // e-list capacity (mean 16, 8 sigma)
static constexpr int NB = N / BT;                 // 64 row/col panels
static constexpr int NSP = NB / 2;                // 32 superpanels
static constexpr int SPB = 16;                    // walker lanes per superpanel
static constexpr int GRID = 512;                  // == 2 blocks/CU x 256 CUs, zero tail

using half8    = __attribute__((ext_vector_type(8))) _Float16;
using floatx16 = __attribute__((ext_vector_type(16))) float;

__device__ __forceinline__ floatx16 zerov() { floatx16 v = {0.f}; return v; }

__device__ __forceinline__ half8 cvt8(float4 v0, float4 v1) {
    half8 h;
    h[0] = (_Float16)v0.x; h[1] = (_Float16)v0.y; h[2] = (_Float16)v0.z; h[3] = (_Float16)v0.w;
    h[4] = (_Float16)v1.x; h[5] = (_Float16)v1.y; h[6] = (_Float16)v1.z; h[7] = (_Float16)v1.w;
    return h;
}

__device__ __forceinline__ float ss8(float4 v0, float4 v1) {
    return v0.x*v0.x + v0.y*v0.y + v0.z*v0.z + v0.w*v0.w
         + v1.x*v1.x + v1.y*v1.y + v1.z*v1.z + v1.w*v1.w;
}

// superpanel k: tiles 0..lenA-1 are (br=k, bc=k+t); rest are (br=63-k, bc=63-k+t-lenA)
__device__ __forceinline__ void dec_sp(int k, int t, int lenA, int& br, int& bc) {
    if (t < lenA) { br = k;      bc = k + t; }
    else          { br = 63 - k; bc = 63 - k + (t - lenA); }
}

// ---- k_prep: anchors + xh (fp16) + sq + ap + GLOBAL e-lists ---------------------------
// egrid is memset to 0x7F (3.396e38) so padded slots self-exclude in the hinge loop.

__launch_bounds__(256)
__global__ void k_prep(const float* __restrict__ x, const int* __restrict__ labels,
                       _Float16* __restrict__ xh, float* __restrict__ sq,
                       int* __restrict__ anchorg, float* __restrict__ ap,
                       int* __restrict__ ecnt, float* __restrict__ egrid,
                       float* __restrict__ out) {
    __shared__ int sAnc[C];
    const int tid = threadIdx.x;
    if (blockIdx.x == 0 && tid == 0) out[0] = 0.f;
    for (int i = tid; i < C; i += 256) sAnc[i] = INT_MAX;
    __syncthreads();
    const int4* lab4 = (const int4*)labels;
    for (int t = tid; t < N / 4; t += 256) {
        int4 lv = lab4[t];
        int base = 4 * t;
        atomicMin(&sAnc[lv.x], base);
        atomicMin(&sAnc[lv.y], base + 1);
        atomicMin(&sAnc[lv.z], base + 2);
        atomicMin(&sAnc[lv.w], base + 3);
    }
    __syncthreads();
    if (tid < 2) {
        int c = blockIdx.x * 2 + tid;
        int a = sAnc[c];
        anchorg[c] = (a == INT_MAX) ? -1 : a;
    }

    const int r = blockIdx.x * 32 + (tid >> 3);
    const int sub = tid & 7;
    const float4* src = (const float4*)(x + (size_t)r * D) + sub * 4;
    half8* dst = (half8*)(xh + (size_t)r * D) + sub * 2;
    half8 hj[2];
    float ssj = 0.f;
#pragma unroll
    for (int i = 0; i < 2; ++i) {
        float4 v0 = src[2 * i], v1 = src[2 * i + 1];
        hj[i] = cvt8(v0, v1);
        dst[i] = hj[i];
        ssj += ss8(v0, v1);
    }
    ssj += __shfl_xor(ssj, 1); ssj += __shfl_xor(ssj, 2); ssj += __shfl_xor(ssj, 4);

    const int lab = labels[r];
    const int a = sAnc[lab];
    const float4* asrc = (const float4*)(x + (size_t)a * D) + sub * 4;
    float ssa = 0.f, dot = 0.f;
#pragma unroll
    for (int i = 0; i < 2; ++i) {
        float4 a0 = asrc[2 * i], a1 = asrc[2 * i + 1];
        half8 ha = cvt8(a0, a1);
        ssa += ss8(a0, a1);
#pragma unroll
        for (int e = 0; e < 8; ++e) dot = fmaf((float)ha[e], (float)hj[i][e], dot);
    }
    ssa += __shfl_xor(ssa, 1); ssa += __shfl_xor(ssa, 2); ssa += __shfl_xor(ssa, 4);
    dot += __shfl_xor(dot, 1); dot += __shfl_xor(dot, 2); dot += __shfl_xor(dot, 4);
    if (sub == 0) {
        float apv = ssa + ssj - 2.f * dot;
        sq[r] = ssj;
        ap[r] = apv;
        if (r != a) {   // append to the class e-list (anchor itself excluded)
            int slot = atomicAdd(&ecnt[lab], 1);
            if (slot < MAXG) egrid[(size_t)lab * MAXG + slot] = apv + HALFA;
        }
    }
}

// ---- k_main: 512 balanced blocks (2/CU exact, zero tail) ------------------------------
// Every block: 1 term1 tile (64 anchors x 128 pts, tile id = blockIdx) THEN walks its
// term2 superpanel lane (k = b>>4, p = b&15; 4-5 tiles). Term2's first-tile loads issue
// right after the term1 MFMA (af regs reused) and hide under the term1 hinge epilogue.
// __launch_bounds__(512,2): R5/R7-proven no-spill point (~68 VGPR).

__launch_bounds__(512, 2)
__global__ void k_main(const _Float16* __restrict__ xh, const int* __restrict__ labels,
                       const int* __restrict__ anchor, const float* __restrict__ sq,
                       const float* __restrict__ ap, const int* __restrict__ ecnt,
                       const float* __restrict__ egrid, float* __restrict__ out) {
    __shared__ __align__(16) _Float16 BsH[GR * SL * 8];   // 33024 B, K-major [granule][row]
    __shared__ __align__(16) float sge[64 * MAXG];        // 12288 B e-lists
    __shared__ float4 rowE[BT];
    __shared__ float4 colE[2][BT];
    __shared__ int   sArow[64];
    __shared__ float sSqA[64];
    __shared__ int   sCnt[64];
    __shared__ float wsum[8];
    half8* Bs = (half8*)BsH;

    const int tid = threadIdx.x;
    const int lane = tid & 63, w = tid >> 6;
    const int m = lane & 31, q = lane >> 5;
    const int sg = tid & 15, sr0 = tid >> 4;   // staging: granule, row base
    float local = 0.f;
    int cnt = 0;                                // hinge slots evaluated (for +h*cnt)

    const int b = blockIdx.x;
    // term1 tile coords (one tile per block: 8 class-panels x 64 j-tiles)
    const int c0 = (b >> 6) * 64, j1 = (b & 63) * BT;
    // term2 walker coords
    const int kk_sp = b >> 4, p = b & 15;
    const int lenA = 64 - kk_sp;

    // ================= phase 0: term1 meta + e-lists + B prefetch =================
    if (tid < 64) {
        int c = c0 + tid;
        int a = anchor[c];
        int ar = (a < 0) ? 0 : a;          // dummy (absent class has cnt 0)
        sArow[tid] = ar;
        sSqA[tid] = sq[ar];
        int n = ecnt[c];
        sCnt[tid] = (n > MAXG) ? MAXG : n;
    }
    {   // bulk-copy 64 class e-lists (globally pre-padded with 3.4e38)
        const float4* srcv = (const float4*)(egrid + (size_t)c0 * MAXG);
        float4* dstv = (float4*)sge;
        dstv[tid] = srcv[tid];
        if (tid < 64 * MAXG / 4 - 512) dstv[tid + 512] = srcv[tid + 512];
    }
    half8 breg[4];
#pragma unroll
    for (int i = 0; i < 4; ++i)
        breg[i] = *((const half8*)(xh + (size_t)(j1 + sr0 + 32 * i) * D) + sg);
    if (tid < BT) {
        int j = j1 + tid;
        colE[0][tid] = make_float4(sq[j], __int_as_float(labels[j]), 0.f, 0.f);
    }
    __syncthreads();

    // ================= phase 1: term1 MFMA =================
    half8 af[8];
    {   // gathered anchor rows; 2 row-groups x 4 col-groups
        int arow = sArow[(w >> 2) * 32 + m];
        const half8* aptr = (const half8*)(xh + (size_t)arow * D) + q;
#pragma unroll
        for (int k = 0; k < 8; ++k) af[k] = aptr[2 * k];
    }
#pragma unroll
    for (int i = 0; i < 4; ++i)
        Bs[sg * SL + sr0 + 32 * i] = breg[i];
    __syncthreads();

    floatx16 acc = zerov();
#pragma unroll
    for (int k = 0; k < 8; ++k) {
        half8 b0 = Bs[(2 * k + q) * SL + (w & 3) * 32 + m];
        acc = __builtin_amdgcn_mfma_f32_32x32x16_f16(af[k], b0, acc, 0, 0, 0);
    }

    // ================= phase 2: prefetch term2 tile0 (hides under term1 epilogue) ====
    int br0, bc0; dec_sp(kk_sp, p, lenA, br0, bc0);
    {
        const half8* aptr = (const half8*)(xh + (size_t)(br0 * BT + (w >> 1) * 32 + m) * D) + q;
#pragma unroll
        for (int k = 0; k < 8; ++k) af[k] = aptr[2 * k];   // af dead after term1 MFMA
#pragma unroll
        for (int i = 0; i < 4; ++i)
            breg[i] = *((const half8*)(xh + (size_t)(bc0 * BT + sr0 + 32 * i) * D) + sg);
        if (tid < BT) {
            int i = br0 * BT + tid;
            int li = labels[i]; int a = anchor[li];
            float sqi = sq[i];
            float e2 = (i == a) ? -1e30f : ap[i] + HALFA - sqi;
            rowE[tid] = make_float4(e2, __int_as_float(li), sqi, 0.f);
        } else if (tid < 2 * BT) {
            int j = bc0 * BT + tid - BT;
            int lj = labels[j]; int a = anchor[lj];
            float sqj = sq[j];
            float e2 = (j == a) ? -1e30f : ap[j] + HALFA - sqj;
            colE[1][tid - BT] = make_float4(e2, __int_as_float(lj), sqj, 0.f);
        }
    }

    // ================= phase 3: term1 hinge epilogue =================
    {
        float4 cj = colE[0][(w & 3) * 32 + m];
        float sqj = cj.x; int labj = __float_as_int(cj.y);
#pragma unroll
        for (int rr = 0; rr < 16; ++rr) {
            int row = (w >> 2) * 32 + (rr & 3) + 8 * (rr >> 2) + 4 * q;
            float Dv = fmaf(-2.f, acc[rr], sSqA[row] + sqj);
            Dv = (labj != c0 + row) ? Dv : 3.0e38f;       // fold label mask into base
            int nf = (sCnt[row] + 3) & ~3;
            cnt += nf;
            for (int gb = 0; gb < nf; gb += 4) {
                float4 ev = *(const float4*)&sge[row * MAXG + gb];
                float u;
                u = ev.x - Dv; local += (__builtin_fabsf(u) < HALFA) ? u : -HALFA;
                u = ev.y - Dv; local += (__builtin_fabsf(u) < HALFA) ? u : -HALFA;
                u = ev.z - Dv; local += (__builtin_fabsf(u) < HALFA) ? u : -HALFA;
                u = ev.w - Dv; local += (__builtin_fabsf(u) < HALFA) ? u : -HALFA;
            }
        }
    }
    __syncthreads();   // term1 done; Bs/colE[0] free for the walker

    // ================= phase 4: term2 superpanel walker =================
    {
        const int wr = w >> 1, wc = w & 1;     // 4 row-groups x 2 col-groups
        int cbuf = 1, cur_br = br0;

        for (int t = p; t < 65; t += SPB) {
            int br, bc; dec_sp(kk_sp, t, lenA, br, bc);
            const int i0 = br * BT;
            const bool diag = (br == bc);

            if (br != cur_br) {                 // at most one seam per block
                cur_br = br;
                const half8* aptr = (const half8*)(xh + (size_t)(i0 + wr * 32 + m) * D) + q;
#pragma unroll
                for (int k8 = 0; k8 < 8; ++k8) af[k8] = aptr[2 * k8];
                if (tid < BT) {
                    int i = i0 + tid;
                    int li = labels[i]; int a = anchor[li];
                    float sqi = sq[i];
                    float e2 = (i == a) ? -1e30f : ap[i] + HALFA - sqi;
                    rowE[tid] = make_float4(e2, __int_as_float(li), sqi, 0.f);
                }
            }

#pragma unroll
            for (int i = 0; i < 4; ++i)
                Bs[sg * SL + sr0 + 32 * i] = breg[i];
            __syncthreads();

            if (t + SPB < 65) {                 // prefetch next tile
                int brn, bcn; dec_sp(kk_sp, t + SPB, lenA, brn, bcn);
                int j0n = bcn * BT;
#pragma unroll
                for (int i = 0; i < 4; ++i)
                    breg[i] = *((const half8*)(xh + (size_t)(j0n + sr0 + 32 * i) * D) + sg);
                if (tid < BT) {
                    int j = j0n + tid;
                    int lj = labels[j]; int a = anchor[lj];
                    float sqj = sq[j];
                    float e2 = (j == a) ? -1e30f : ap[j] + HALFA - sqj;
                    colE[cbuf ^ 1][tid] = make_float4(e2, __int_as_float(lj), sqj, 0.f);
                }
            }

            floatx16 acc0 = zerov(), acc1 = zerov();
#pragma unroll
            for (int k8 = 0; k8 < 8; ++k8) {
                half8 b0 = Bs[(2 * k8 + q) * SL + wc * 64 + m];
                half8 b1 = Bs[(2 * k8 + q) * SL + wc * 64 + 32 + m];
                acc0 = __builtin_amdgcn_mfma_f32_32x32x16_f16(af[k8], b0, acc0, 0, 0, 0);
                acc1 = __builtin_amdgcn_mfma_f32_32x32x16_f16(af[k8], b1, acc1, 0, 0, 0);
            }

            float sqjv[2], e2j[2]; int labj[2];
            { float4 cj = colE[cbuf][wc * 64 + m];      e2j[0] = cj.x; labj[0] = __float_as_int(cj.y); sqjv[0] = cj.z; }
            { float4 cj = colE[cbuf][wc * 64 + 32 + m]; e2j[1] = cj.x; labj[1] = __float_as_int(cj.y); sqjv[1] = cj.z; }

#pragma unroll
            for (int rr = 0; rr < 16; ++rr) {
                int row = wr * 32 + (rr & 3) + 8 * (rr >> 2) + 4 * q;
                float4 re = rowE[row];
                float e2i = re.x, sqi = re.z;
                int labi = __float_as_int(re.y);
#pragma unroll
                for (int tn = 0; tn < 2; ++tn) {
                    float dot = (tn == 0) ? acc0[rr] : acc1[rr];
                    bool ne = (labi != labj[tn]);
                    float b1v = ne ? (e2i - sqjv[tn]) : 3.0e38f;
                    float u2 = fmaf(2.f, dot, b1v);
                    local += (__builtin_fabsf(u2) < HALFA) ? u2 : -HALFA;
                    if (!diag) {
                        float b2v = ne ? (e2j[tn] - sqi) : 3.0e38f;
                        float u2b = fmaf(2.f, dot, b2v);
                        local += (__builtin_fabsf(u2b) < HALFA) ? u2b : -HALFA;
                    }
                }
            }
            cnt += diag ? 32 : 64;
            cbuf ^= 1;
            __syncthreads();
        }
    }

    // compensation for the -HALFA branchless accumulation, then block reduce
    local += HALFA * (float)cnt;
#pragma unroll
    for (int off = 32; off; off >>= 1) local += __shfl_down(local, off);
    if (lane == 0) wsum[w] = local;
    __syncthreads();
    if (tid == 0) {
        float s = 0.f;
#pragma unroll
        for (int i = 0; i < 8; ++i) s += wsum[i];
        atomicAdd(out, s);
    }
}

// ---------------- launch ----------------

extern "C" void kernel_launch(void* const* d_in, const int* in_sizes, int n_in,
                              void* d_out, int out_size, void* d_ws, size_t ws_size,
                              hipStream_t stream) {
    const float* x = (const float*)d_in[0];
    const int* labels = (const int*)d_in[1];
    float* out = (float*)d_out;

    char* p = (char*)d_ws;
    int* anchor = (int*)p;        p += C * 4;
    float* sq = (float*)p;        p += N * 4;
    float* ap = (float*)p;        p += N * 4;
    int* ecnt = (int*)p;          p += C * 4;
    float* egrid = (float*)p;     p += (size_t)C * MAXG * 4;
    p = (char*)(((uintptr_t)p + 255) & ~(uintptr_t)255);
    _Float16* xh = (_Float16*)p;  // N*D*2 = 2 MB

    hipMemsetAsync(ecnt, 0, C * 4, stream);
    hipMemsetAsync(egrid, 0x7F, (size_t)C * MAXG * 4, stream);   // 3.396e38 pads
    k_prep<<<N / 32, 256, 0, stream>>>(x, labels, xh, sq, anchor, ap, ecnt, egrid, out);
    k_main<<<GRID, 512, 0, stream>>>(xh, labels, anchor, sq, ap, ecnt, egrid, out);
}